// Round 2
// baseline (586.956 us; speedup 1.0000x reference)
//
#include <hip/hip_runtime.h>
#include <hip/hip_bf16.h>

typedef __attribute__((ext_vector_type(8))) short short8;
typedef __attribute__((ext_vector_type(4))) float f32x4;
typedef __attribute__((ext_vector_type(2))) float f32x2;

#define NCELL 8192
#define NGENE 10000
#define KD 32
#define ZD 100
#define HD 256
#define GD 100   // z_dim of output (gen_Z rows)

__device__ __forceinline__ float gelu_exact(float x) {
    return 0.5f * x * (1.0f + erff(x * 0.70710678118654752f));
}

// ---------------- Kernel 1: key_t[32][8192]; also Kmax2 = max_c ||k_c||^2 (atomicMax on uint bits)
__global__ void key_kernel(const float* __restrict__ rawZ,
                           const float* __restrict__ Wz1, const float* __restrict__ bz1,
                           const float* __restrict__ Wz2, const float* __restrict__ bz2,
                           float* __restrict__ key_t, unsigned* __restrict__ kmax2u) {
    __shared__ float z[8][ZD];
    __shared__ float h[8][HD];
    const int t = threadIdx.x;
    const int c0 = blockIdx.x * 8;
    for (int idx = t; idx < 8 * ZD; idx += 256) {
        int cell = idx / ZD, i = idx - cell * ZD;
        z[cell][i] = rawZ[i * NCELL + c0 + cell];
    }
    __syncthreads();
    float a[8];
#pragma unroll
    for (int cl = 0; cl < 8; ++cl) a[cl] = bz1[t];
    for (int i = 0; i < ZD; ++i) {
        float wv = Wz1[i * HD + t];
#pragma unroll
        for (int cl = 0; cl < 8; ++cl) a[cl] += z[cl][i] * wv;
    }
#pragma unroll
    for (int cl = 0; cl < 8; ++cl) h[cl][t] = gelu_exact(a[cl]);
    __syncthreads();
    const int cell = t >> 5, kk = t & 31;
    float b = bz2[kk];
    for (int j = 0; j < HD; ++j) b += h[cell][j] * Wz2[j * KD + kk];
    key_t[kk * NCELL + c0 + cell] = b;
    // per-cell squared norm -> global max (positive floats: uint order == float order)
    float sq = b * b;
#pragma unroll
    for (int off = 16; off > 0; off >>= 1) sq += __shfl_xor(sq, off, 32);
    if (kk == 0) atomicMax(kmax2u, __float_as_uint(sq));
}

// ---------------- Kernel 2: qs[10000][32] (pre-scaled by 1/sqrt(32)); M_g = ||q~_g||*Kmax + 25
__global__ void query_kernel(const float* __restrict__ Grep,
                             const float* __restrict__ Wg1, const float* __restrict__ bg1,
                             const float* __restrict__ Wg2, const float* __restrict__ bg2,
                             const unsigned* __restrict__ kmax2u,
                             float* __restrict__ qs, float* __restrict__ Mg) {
    __shared__ float gr[8][GD];
    __shared__ float hq[8][KD];
    const int t = threadIdx.x;
    const int g0 = blockIdx.x * 8;
    for (int idx = t; idx < 8 * GD; idx += 256) {
        int ge = idx / GD, i = idx - ge * GD;
        gr[ge][i] = Grep[(g0 + ge) * GD + i];
    }
    __syncthreads();
    const int ge = t >> 5, kk = t & 31;
    float a = bg1[kk];
    for (int i = 0; i < GD; ++i) a += gr[ge][i] * Wg1[i * KD + kk];
    hq[ge][kk] = gelu_exact(a);
    __syncthreads();
    float b = bg2[kk];
#pragma unroll
    for (int j = 0; j < KD; ++j) b += hq[ge][j] * Wg2[j * KD + kk];
    float qv = b * 0.17677669529663687f; // fold 1/sqrt(d_k)
    qs[(g0 + ge) * KD + kk] = qv;
    float sq = qv * qv;
#pragma unroll
    for (int off = 16; off > 0; off >>= 1) sq += __shfl_xor(sq, off, 32);
    if (kk == 0) {
        float km2 = __uint_as_float(*kmax2u);
        // static softmax shift: provable upper bound on max_c(q~.k_c + gumbel); exp(l-M)<=1,
        // undershoot impossible (Cauchy-Schwarz + gumbel<25 w.h.p.; overflow needs gumbel>113)
        Mg[g0 + ge] = sqrtf(sq * km2) + 25.0f;
    }
}

// ---------------- Kernel 3: genZB — gen_Z repacked to bf16 in MFMA B-fragment-linear order.
__global__ void vprep_kernel(const float* __restrict__ genZ, ushort* __restrict__ genZB) {
    int o = blockIdx.x * 256 + threadIdx.x; // 1,048,576 total
    int j = o & 7;
    int l = (o >> 3) & 63;
    int db = (o >> 9) & 7;
    int cb = o >> 12;
    int c = cb * 32 + ((l >> 4) & 3) * 8 + j;
    int d = db * 16 + (l & 15);
    float v = (d < GD) ? genZ[d * NCELL + c] : 0.0f;
    __hip_bfloat16 bv = __float2bfloat16(v);
    genZB[o] = *reinterpret_cast<ushort*>(&bv);
}

// ---------------- Kernel 4: fused attention, static-max softmax (no online rescale)
// 512 thr = 8 waves; 16 genes/block; cell tiles of 1024 (8 iters); wave w: cells [128w,128w+128)
// (2 cells/lane) for scores, d-tile [16w,16w+16) for PV.
__launch_bounds__(512)
__global__ void fused_kernel(const float* __restrict__ gumbel,
                             const float* __restrict__ key_t,
                             const float* __restrict__ qs,
                             const float* __restrict__ Mg,
                             const ushort* __restrict__ genZB,
                             float* __restrict__ out) {
    __shared__ __align__(16) ushort p_lds[16 * 1024];   // 32 KB, A-fragment-linear + XOR swizzle
    __shared__ __align__(16) float q_lds[16 * KD];      // 2 KB
    __shared__ float M_lds[16];
    __shared__ float Lred[8][16];
    __shared__ __align__(16) float Linv_lds[16];

    const int t = threadIdx.x;
    const int lane = t & 63;
    const int w = t >> 6;
    const int g0 = blockIdx.x * 16;

    q_lds[t] = qs[g0 * KD + t];           // 512 == 16*KD exactly
    if (t < 16) M_lds[t] = Mg[g0 + t];

    float L[16];
#pragma unroll
    for (int g = 0; g < 16; ++g) L[g] = 0.f;
    f32x4 accE = {0.f, 0.f, 0.f, 0.f}, accO = {0.f, 0.f, 0.f, 0.f};

    // P write base: cell-local cl0 = 128w + 2*lane -> (kb, bsub, jj); byte = kb*1024+bsub*256+g*16+jj*2
    const int cl0 = 128 * w + 2 * lane;
    const int kbw = cl0 >> 5;
    const int rr = cl0 & 31;
    const int Cbase = kbw * 1024 + (rr >> 3) * 256 + (rr & 7) * 2;
    const int Sx = ((Cbase >> 8) & 7) << 4;   // XOR swizzle: spreads (kb0,bsub) into bank bits

    for (int it = 0; it < 8; ++it) {
        const int c0 = it * 1024 + cl0;
        f32x2 key2[KD];
#pragma unroll
        for (int k = 0; k < KD; ++k)
            key2[k] = *reinterpret_cast<const f32x2*>(key_t + k * NCELL + c0);
        __syncthreads();   // prev PV reads done (and q_lds staged, first iter)
#pragma unroll
        for (int g = 0; g < 16; ++g) {
            const f32x4* qv = reinterpret_cast<const f32x4*>(q_lds + g * KD);
            f32x2 gu = *reinterpret_cast<const f32x2*>(gumbel + (size_t)(g0 + g) * NCELL + c0);
            float s0 = gu.x, s1 = gu.y;   // logits start from gumbel (tau=1)
#pragma unroll
            for (int kq = 0; kq < 8; ++kq) {
                f32x4 q4 = qv[kq];
#pragma unroll
                for (int e = 0; e < 4; ++e) {
                    float qk = q4[e];
                    s0 = fmaf(qk, key2[kq * 4 + e].x, s0);
                    s1 = fmaf(qk, key2[kq * 4 + e].y, s1);
                }
            }
            float Mgv = M_lds[g];
            float p0 = __expf(s0 - Mgv);
            float p1 = __expf(s1 - Mgv);
            L[g] += p0 + p1;
            __hip_bfloat16 h0 = __float2bfloat16(p0), h1 = __float2bfloat16(p1);
            unsigned pu = (unsigned)(*reinterpret_cast<ushort*>(&h0)) |
                          ((unsigned)(*reinterpret_cast<ushort*>(&h1)) << 16);
            int addr = (Cbase + (g << 4)) ^ Sx;
            *reinterpret_cast<unsigned*>(reinterpret_cast<char*>(p_lds) + addr) = pu;
        }
        __syncthreads();
        // ---- PV: acc[16 genes x d-tile w] += P(16x1024) @ V(1024x16), 32 k-blocks
        const short8* bfp = reinterpret_cast<const short8*>(genZB);
        const char* pb8 = reinterpret_cast<const char*>(p_lds);
#pragma unroll
        for (int kb = 0; kb < 32; ++kb) {
            int rbyte = kb * 1024 + lane * 16;
            rbyte ^= ((rbyte >> 8) & 7) << 4;
            short8 a = *reinterpret_cast<const short8*>(pb8 + rbyte);
            short8 b = bfp[((it * 32 + kb) * 8 + w) * 64 + lane];
            if (kb & 1) accO = __builtin_amdgcn_mfma_f32_16x16x32_bf16(a, b, accO, 0, 0, 0);
            else        accE = __builtin_amdgcn_mfma_f32_16x16x32_bf16(a, b, accE, 0, 0, 0);
        }
    }
    // ---- final L reduce (lanes hold disjoint-cell partials)
#pragma unroll
    for (int g = 0; g < 16; ++g) {
#pragma unroll
        for (int off = 32; off > 0; off >>= 1) L[g] += __shfl_xor(L[g], off, 64);
    }
    if (lane == 0) {
#pragma unroll
        for (int g = 0; g < 16; ++g) Lred[w][g] = L[g];
    }
    __syncthreads();
    if (t < 16) {
        float s = 0.f;
#pragma unroll
        for (int ww = 0; ww < 8; ++ww) s += Lred[ww][t];
        Linv_lds[t] = 1.0f / s;
    }
    __syncthreads();
    f32x4 acc = accE + accO;
    const int d = 16 * w + (lane & 15);
    if (d < GD) {
        const int gl0 = (lane >> 4) * 4;  // C/D: col=lane&15 (d), row=(lane>>4)*4+r (gene)
        f32x4 li = *reinterpret_cast<const f32x4*>(&Linv_lds[gl0]);
        f32x4 o = {acc.x * li.x, acc.y * li.y, acc.z * li.z, acc.w * li.w};
        *reinterpret_cast<f32x4*>(out + (size_t)d * NGENE + g0 + gl0) = o;
    }
}

extern "C" void kernel_launch(void* const* d_in, const int* in_sizes, int n_in,
                              void* d_out, int out_size, void* d_ws, size_t ws_size,
                              hipStream_t stream) {
    const float* rawZ  = (const float*)d_in[0];
    const float* genZ  = (const float*)d_in[1];
    const float* Grep  = (const float*)d_in[2];
    const float* gumb  = (const float*)d_in[3];
    const float* Wz1   = (const float*)d_in[4];
    const float* bz1   = (const float*)d_in[5];
    const float* Wz2   = (const float*)d_in[6];
    const float* bz2   = (const float*)d_in[7];
    const float* Wg1   = (const float*)d_in[8];
    const float* bg1   = (const float*)d_in[9];
    const float* Wg2   = (const float*)d_in[10];
    const float* bg2   = (const float*)d_in[11];
    float* out = (float*)d_out;

    // ws: key_t 1MB | qs 1.28MB | genZB 2MB | Mg 40KB | kmax2u 4B   (~4.47 MB)
    char* ws = (char*)d_ws;
    float*    key_t = (float*)ws;
    float*    qs    = (float*)(ws + 1048576);
    ushort*   genZB = (ushort*)(ws + 1048576 + 1280000);
    float*    MgA   = (float*)(ws + 1048576 + 1280000 + 2097152);
    unsigned* kmax  = (unsigned*)(ws + 1048576 + 1280000 + 2097152 + 40000);

    hipMemsetAsync(kmax, 0, 4, stream);
    hipLaunchKernelGGL(key_kernel,   dim3(NCELL / 8), dim3(256), 0, stream,
                       rawZ, Wz1, bz1, Wz2, bz2, key_t, kmax);
    hipLaunchKernelGGL(query_kernel, dim3(NGENE / 8), dim3(256), 0, stream,
                       Grep, Wg1, bg1, Wg2, bg2, kmax, qs, MgA);
    hipLaunchKernelGGL(vprep_kernel, dim3((256 * 8 * 64 * 8) / 256), dim3(256), 0, stream,
                       genZ, genZB);
    hipLaunchKernelGGL(fused_kernel, dim3(NGENE / 16), dim3(512), 0, stream,
                       gumb, key_t, qs, MgA, genZB, out);
}

// Round 3
// 254.451 us; speedup vs baseline: 2.3068x; 2.3068x over previous
//
#include <hip/hip_runtime.h>
#include <hip/hip_bf16.h>

typedef __attribute__((ext_vector_type(8))) short short8;
typedef __attribute__((ext_vector_type(4))) float f32x4;

#define NCELL 8192
#define NGENE 10000
#define KD 32
#define ZD 100
#define HD 256
#define GD 100   // z_dim of output (gen_Z rows)

__device__ __forceinline__ float gelu_exact(float x) {
    return 0.5f * x * (1.0f + erff(x * 0.70710678118654752f));
}
__device__ __forceinline__ ushort bf16bits(float x) {
    __hip_bfloat16 h = __float2bfloat16(x);
    return *reinterpret_cast<ushort*>(&h);
}

// ---------------- Kernel 1: keys -> bf16 hi/lo B-fragments (col=cell&15, k=8*(l'>>4)+j),
// plus Kmax2 = max_c ||k_c||^2
__global__ void key_kernel(const float* __restrict__ rawZ,
                           const float* __restrict__ Wz1, const float* __restrict__ bz1,
                           const float* __restrict__ Wz2, const float* __restrict__ bz2,
                           ushort* __restrict__ khiB, ushort* __restrict__ kloB,
                           unsigned* __restrict__ kmax2u) {
    __shared__ float z[8][ZD];
    __shared__ float h[8][HD];
    const int t = threadIdx.x;
    const int c0 = blockIdx.x * 8;
    for (int idx = t; idx < 8 * ZD; idx += 256) {
        int cell = idx / ZD, i = idx - cell * ZD;
        z[cell][i] = rawZ[i * NCELL + c0 + cell];
    }
    __syncthreads();
    float a[8];
#pragma unroll
    for (int cl = 0; cl < 8; ++cl) a[cl] = bz1[t];
    for (int i = 0; i < ZD; ++i) {
        float wv = Wz1[i * HD + t];
#pragma unroll
        for (int cl = 0; cl < 8; ++cl) a[cl] += z[cl][i] * wv;
    }
#pragma unroll
    for (int cl = 0; cl < 8; ++cl) h[cl][t] = gelu_exact(a[cl]);
    __syncthreads();
    const int cell = t >> 5, kk = t & 31;
    float b = bz2[kk];
    for (int j = 0; j < HD; ++j) b += h[cell][j] * Wz2[j * KD + kk];
    const int c = c0 + cell;
    __hip_bfloat16 hi = __float2bfloat16(b);
    float hif = __bfloat162float(hi);
    int idx = ((c >> 4) * 64 + (c & 15) + 16 * (kk >> 3)) * 8 + (kk & 7);
    khiB[idx] = *reinterpret_cast<ushort*>(&hi);
    kloB[idx] = bf16bits(b - hif);
    float sq = b * b;
#pragma unroll
    for (int off = 16; off > 0; off >>= 1) sq += __shfl_xor(sq, off, 32);
    if (kk == 0) atomicMax(kmax2u, __float_as_uint(sq));
}

// ---------------- Kernel 2: q -> bf16 hi/lo A-fragments (row=g&15, k=8*(l'>>4)+j), Mg bound
__global__ void query_kernel(const float* __restrict__ Grep,
                             const float* __restrict__ Wg1, const float* __restrict__ bg1,
                             const float* __restrict__ Wg2, const float* __restrict__ bg2,
                             const unsigned* __restrict__ kmax2u,
                             ushort* __restrict__ qAhi, ushort* __restrict__ qAlo,
                             float* __restrict__ Mg) {
    __shared__ float gr[8][GD];
    __shared__ float hq[8][KD];
    const int t = threadIdx.x;
    const int g0 = blockIdx.x * 8;
    for (int idx = t; idx < 8 * GD; idx += 256) {
        int ge = idx / GD, i = idx - ge * GD;
        gr[ge][i] = Grep[(g0 + ge) * GD + i];
    }
    __syncthreads();
    const int ge = t >> 5, kk = t & 31;
    float a = bg1[kk];
    for (int i = 0; i < GD; ++i) a += gr[ge][i] * Wg1[i * KD + kk];
    hq[ge][kk] = gelu_exact(a);
    __syncthreads();
    float b = bg2[kk];
#pragma unroll
    for (int j = 0; j < KD; ++j) b += hq[ge][j] * Wg2[j * KD + kk];
    float qv = b * 0.17677669529663687f; // fold 1/sqrt(d_k)
    const int g = g0 + ge;
    __hip_bfloat16 hi = __float2bfloat16(qv);
    float hif = __bfloat162float(hi);
    int idx = ((g >> 4) * 64 + (g & 15) + 16 * (kk >> 3)) * 8 + (kk & 7);
    qAhi[idx] = *reinterpret_cast<ushort*>(&hi);
    qAlo[idx] = bf16bits(qv - hif);
    float sq = qv * qv;
#pragma unroll
    for (int off = 16; off > 0; off >>= 1) sq += __shfl_xor(sq, off, 32);
    if (kk == 0) {
        float km2 = __uint_as_float(*kmax2u);
        // static softmax shift: upper bound on max_c(q.k_c + gumbel); exp(l-M) <= 1
        Mg[g] = sqrtf(sq * km2) + 25.0f;
    }
}

// ---------------- Kernel 3: genZB — gen_Z bf16, PV B-fragment order (unchanged, validated)
__global__ void vprep_kernel(const float* __restrict__ genZ, ushort* __restrict__ genZB) {
    int o = blockIdx.x * 256 + threadIdx.x; // 1,048,576 total
    int j = o & 7;
    int l = (o >> 3) & 63;
    int db = (o >> 9) & 7;
    int cb = o >> 12;
    int c = cb * 32 + ((l >> 4) & 3) * 8 + j;
    int d = db * 16 + (l & 15);
    float v = (d < GD) ? genZ[d * NCELL + c] : 0.0f;
    genZB[o] = bf16bits(v);
}

// ---------------- Kernel 4: fused. S via 3-term bf16-split MFMA, static-max exp, PV MFMA.
// 512 thr = 8 waves; 16 genes/block; chunks of 256 cells; wave w scores c-tiles {2w,2w+1},
// owns PV d-tile [16w,16w+16). One barrier per chunk (ping-pong P).
__launch_bounds__(512)
__global__ void fused_kernel(const float* __restrict__ gumbel,
                             const ushort* __restrict__ khiB, const ushort* __restrict__ kloB,
                             const ushort* __restrict__ qAhi, const ushort* __restrict__ qAlo,
                             const float* __restrict__ Mg,
                             const ushort* __restrict__ genZB,
                             float* __restrict__ out) {
    __shared__ __align__(16) ushort p_lds[2 * 8192];  // 32 KB ping-pong, swizzled A-frag order
    __shared__ float M_lds[16];
    __shared__ float Lred[8][16];
    __shared__ __align__(16) float Linv_lds[16];

    const int t = threadIdx.x, lane = t & 63, w = t >> 6;
    const int g0 = blockIdx.x * 16;

    if (t < 16) M_lds[t] = Mg[g0 + t];
    short8 qhi = *reinterpret_cast<const short8*>(qAhi + (size_t)blockIdx.x * 512 + lane * 8);
    short8 qlo = *reinterpret_cast<const short8*>(qAlo + (size_t)blockIdx.x * 512 + lane * 8);
    __syncthreads();
    float Mvec[4];
#pragma unroll
    for (int r = 0; r < 4; ++r) Mvec[r] = M_lds[4 * (lane >> 4) + r];

    float L[4] = {0.f, 0.f, 0.f, 0.f};
    f32x4 acc = {0.f, 0.f, 0.f, 0.f};
    const float* grow = gumbel + (size_t)(g0 + 4 * (lane >> 4)) * NCELL + (lane & 15);
    // P write byte (pre-swizzle) = pp*16384 + w*1024 + l'*16 + j*2,
    // l' = g_row + 16*(2e + ((lane&15)>>3)), j = lane&7
    const int wrbase = w * 1024 + ((lane & 15) >> 3) * 256 + (lane & 7) * 2;
    const short8* bfp = reinterpret_cast<const short8*>(genZB);
    char* pb = reinterpret_cast<char*>(p_lds);

    int pp = 0;
    for (int chunk = 0; chunk < 32; ++chunk) {
        const int ct0 = chunk * 16 + 2 * w;
        // ---- issue all loads for this chunk's score phase
        short8 kh0 = *reinterpret_cast<const short8*>(khiB + ct0 * 512 + lane * 8);
        short8 kl0 = *reinterpret_cast<const short8*>(kloB + ct0 * 512 + lane * 8);
        short8 kh1 = *reinterpret_cast<const short8*>(khiB + (ct0 + 1) * 512 + lane * 8);
        short8 kl1 = *reinterpret_cast<const short8*>(kloB + (ct0 + 1) * 512 + lane * 8);
        float gu0[4], gu1[4];
#pragma unroll
        for (int r = 0; r < 4; ++r) {
            gu0[r] = grow[(size_t)r * NCELL + ct0 * 16];
            gu1[r] = grow[(size_t)r * NCELL + (ct0 + 1) * 16];
        }
        // ---- scores, 2 c-tiles of 16 cells
        f32x4 s0 = {0.f, 0.f, 0.f, 0.f}, s1 = {0.f, 0.f, 0.f, 0.f};
        s0 = __builtin_amdgcn_mfma_f32_16x16x32_bf16(qhi, kh0, s0, 0, 0, 0);
        s0 = __builtin_amdgcn_mfma_f32_16x16x32_bf16(qhi, kl0, s0, 0, 0, 0);
        s0 = __builtin_amdgcn_mfma_f32_16x16x32_bf16(qlo, kh0, s0, 0, 0, 0);
        s1 = __builtin_amdgcn_mfma_f32_16x16x32_bf16(qhi, kh1, s1, 0, 0, 0);
        s1 = __builtin_amdgcn_mfma_f32_16x16x32_bf16(qhi, kl1, s1, 0, 0, 0);
        s1 = __builtin_amdgcn_mfma_f32_16x16x32_bf16(qlo, kh1, s1, 0, 0, 0);
        const int base = pp * 16384 + wrbase + 64 * (lane >> 4);
#pragma unroll
        for (int r = 0; r < 4; ++r) {
            float p0 = __expf(s0[r] + gu0[r] - Mvec[r]);
            float p1 = __expf(s1[r] + gu1[r] - Mvec[r]);
            L[r] += p0 + p1;
            int b0 = base + 16 * r;           // e = 0
            int b1 = b0 + 512;                // e = 1
            b0 ^= ((b0 >> 8) & 7) << 4;
            b1 ^= ((b1 >> 8) & 7) << 4;
            *reinterpret_cast<ushort*>(pb + b0) = bf16bits(p0);
            *reinterpret_cast<ushort*>(pb + b1) = bf16bits(p1);
        }
        __syncthreads();
        // ---- PV over this chunk: 8 k-blocks of 32 cells
        if (w < 7) {   // d-tile 7 is all-pad (d >= 112)
#pragma unroll
            for (int kb = 0; kb < 8; ++kb) {
                int rbyte = pp * 16384 + kb * 1024 + lane * 16;
                rbyte ^= ((rbyte >> 8) & 7) << 4;
                short8 a = *reinterpret_cast<const short8*>(pb + rbyte);
                short8 b = bfp[((chunk * 8 + kb) * 8 + w) * 64 + lane];
                acc = __builtin_amdgcn_mfma_f32_16x16x32_bf16(a, b, acc, 0, 0, 0);
            }
        }
        pp ^= 1;
    }
    // ---- L reduction: lanes sharing (lane>>4) hold disjoint-cell partials of same 4 genes
#pragma unroll
    for (int r = 0; r < 4; ++r) {
        float v = L[r];
        v += __shfl_xor(v, 1, 64);
        v += __shfl_xor(v, 2, 64);
        v += __shfl_xor(v, 4, 64);
        v += __shfl_xor(v, 8, 64);
        L[r] = v;
    }
    if ((lane & 15) == 0) {
#pragma unroll
        for (int r = 0; r < 4; ++r) Lred[w][4 * (lane >> 4) + r] = L[r];
    }
    __syncthreads();
    if (t < 16) {
        float s = 0.f;
#pragma unroll
        for (int ww = 0; ww < 8; ++ww) s += Lred[ww][t];
        Linv_lds[t] = 1.0f / s;
    }
    __syncthreads();
    const int d = 16 * w + (lane & 15);
    if (d < GD) {
        const int gl0 = (lane >> 4) * 4;  // C/D: col=lane&15 (d), row=(lane>>4)*4+r (gene)
        f32x4 li = *reinterpret_cast<const f32x4*>(&Linv_lds[gl0]);
        f32x4 o = {acc.x * li.x, acc.y * li.y, acc.z * li.z, acc.w * li.w};
        *reinterpret_cast<f32x4*>(out + (size_t)d * NGENE + g0 + gl0) = o;
    }
}

extern "C" void kernel_launch(void* const* d_in, const int* in_sizes, int n_in,
                              void* d_out, int out_size, void* d_ws, size_t ws_size,
                              hipStream_t stream) {
    const float* rawZ  = (const float*)d_in[0];
    const float* genZ  = (const float*)d_in[1];
    const float* Grep  = (const float*)d_in[2];
    const float* gumb  = (const float*)d_in[3];
    const float* Wz1   = (const float*)d_in[4];
    const float* bz1   = (const float*)d_in[5];
    const float* Wz2   = (const float*)d_in[6];
    const float* bz2   = (const float*)d_in[7];
    const float* Wg1   = (const float*)d_in[8];
    const float* bg1   = (const float*)d_in[9];
    const float* Wg2   = (const float*)d_in[10];
    const float* bg2   = (const float*)d_in[11];
    float* out = (float*)d_out;

    // ws: khiB 512K | kloB 512K | qAhi 640K | qAlo 640K | genZB 2M | Mg 40K | kmax 4B
    char* ws = (char*)d_ws;
    ushort*   khiB = (ushort*)ws;
    ushort*   kloB = (ushort*)(ws + 524288);
    ushort*   qAhi = (ushort*)(ws + 1048576);
    ushort*   qAlo = (ushort*)(ws + 1048576 + 655360);
    ushort*   genZB = (ushort*)(ws + 1048576 + 2 * 655360);
    float*    MgA  = (float*)(ws + 1048576 + 2 * 655360 + 2097152);
    unsigned* kmax = (unsigned*)(ws + 1048576 + 2 * 655360 + 2097152 + 40960);

    hipMemsetAsync(kmax, 0, 4, stream);
    hipLaunchKernelGGL(key_kernel,   dim3(NCELL / 8), dim3(256), 0, stream,
                       rawZ, Wz1, bz1, Wz2, bz2, khiB, kloB, kmax);
    hipLaunchKernelGGL(query_kernel, dim3(NGENE / 8), dim3(256), 0, stream,
                       Grep, Wg1, bg1, Wg2, bg2, kmax, qAhi, qAlo, MgA);
    hipLaunchKernelGGL(vprep_kernel, dim3((256 * 8 * 64 * 8) / 256), dim3(256), 0, stream,
                       genZ, genZB);
    hipLaunchKernelGGL(fused_kernel, dim3(NGENE / 16), dim3(512), 0, stream,
                       gumb, khiB, kloB, qAhi, qAlo, MgA, genZB, out);
}